// Round 1
// baseline (3885.362 us; speedup 1.0000x reference)
//
#include <hip/hip_runtime.h>

#define N_ 8192
#define I_ 1024
#define O_ 1024
#define P_ 8
#define C_ 64

// ---------------------------------------------------------------------------
// Kernel A0: proto_sq[o*8+p] = sum_c protos[o,p,c]^2   (fp32, tiny)
// ---------------------------------------------------------------------------
__global__ void psq_kernel(const float* __restrict__ protos, float* __restrict__ psq) {
    const int idx = blockIdx.x * 256 + threadIdx.x;  // 0..8191
    const float* pr = protos + (size_t)idx * C_;
    float s = 0.f;
    #pragma unroll
    for (int c = 0; c < C_; ++c) s = fmaf(pr[c], pr[c], s);
    psq[idx] = s;
}

// ---------------------------------------------------------------------------
// Kernel A: best[o][n] = argmin_p ( proto_sq[o,p] - 2 * <protos[o,p,:], ctx[n,:]> )
// fp32 pass with margin check; fp64 refine (exact) when margin < 4e-3.
// WG = 512 threads (8 waves). Tile: 128 n x 8 o. ctx tile in LDS (stride 68).
// ---------------------------------------------------------------------------
__global__ __launch_bounds__(512, 4)
void argmin_kernel(const float* __restrict__ ctx, const float* __restrict__ protos,
                   const float* __restrict__ psq, unsigned char* __restrict__ best) {
    __shared__ float ctx_lds[128 * 68];  // 34,816 B
    const int o0 = blockIdx.x * 8;
    const int n0 = blockIdx.y * 128;
    const int tid = threadIdx.x;

    // cooperative load: 128 rows x 16 float4, coalesced (4 rows x 256B per wave)
    for (int it = tid; it < 128 * 16; it += 512) {
        const int row = it >> 4, c4 = it & 15;
        const float4 v = *(const float4*)(ctx + (size_t)(n0 + row) * C_ + c4 * 4);
        *(float4*)&ctx_lds[row * 68 + c4 * 4] = v;
    }
    __syncthreads();

    const int w = tid >> 6, l = tid & 63;
    const int o = o0 + w;                      // one o per wave -> proto loads broadcast
    const float* pr = protos + (size_t)o * (P_ * C_);

    float g[2][8];
    #pragma unroll
    for (int j = 0; j < 2; ++j)
        #pragma unroll
        for (int p = 0; p < 8; ++p) g[j][p] = 0.f;

    #pragma unroll 1
    for (int cc = 0; cc < C_; cc += 4) {
        float4 x[2];
        #pragma unroll
        for (int j = 0; j < 2; ++j)
            x[j] = *(const float4*)&ctx_lds[(l + 64 * j) * 68 + cc];
        #pragma unroll
        for (int p = 0; p < 8; ++p) {
            const float4 wv = *(const float4*)(pr + p * C_ + cc);
            #pragma unroll
            for (int j = 0; j < 2; ++j) {
                float a = g[j][p];
                a = fmaf(wv.x, x[j].x, a);
                a = fmaf(wv.y, x[j].y, a);
                a = fmaf(wv.z, x[j].z, a);
                a = fmaf(wv.w, x[j].w, a);
                g[j][p] = a;
            }
        }
    }

    float ps[8];
    #pragma unroll
    for (int p = 0; p < 8; ++p) ps[p] = psq[o * 8 + p];

    #pragma unroll
    for (int j = 0; j < 2; ++j) {
        float b1 = 3.4e38f, b2 = 3.4e38f;
        int bi = 0;
        #pragma unroll
        for (int p = 0; p < 8; ++p) {
            const float f = fmaf(-2.f, g[j][p], ps[p]);
            if (f < b1) { b2 = b1; b1 = f; bi = p; }
            else if (f < b2) { b2 = f; }
        }
        if (b2 - b1 < 4e-3f) {
            // fp64 refine: exact argmin (products of fp32 are exact in fp64)
            double d1 = 1e300;
            int bi2 = 0;
            for (int p = 0; p < 8; ++p) {
                double s = 0.0;
                const float* prow = pr + p * C_;
                const float* crow = &ctx_lds[(l + 64 * j) * 68];
                for (int c = 0; c < C_; ++c) {
                    const double pv = (double)prow[c];
                    const double cv = (double)crow[c];
                    s += pv * (pv - 2.0 * cv);
                }
                if (s < d1) { d1 = s; bi2 = p; }
            }
            bi = bi2;
        }
        best[(size_t)o * N_ + (n0 + l + 64 * j)] = (unsigned char)bi;
    }
}

// ---------------------------------------------------------------------------
// Kernel B: out[n,o] = <W[o, best[o,n], :], X[n,:]> + bias[o, best[o,n]]
// WG = 256 threads, tile 256 n x 32 o. X staged in LDS (K-chunks of 32,
// stride 36 floats). Weight loads: <=8 distinct addresses per wave instr.
// ---------------------------------------------------------------------------
__global__ __launch_bounds__(256, 3)
void gemm_sel_kernel(const float* __restrict__ X, const float* __restrict__ W,
                     const float* __restrict__ bias, const unsigned char* __restrict__ best,
                     float* __restrict__ out) {
    __shared__ float x_lds[256 * 36];  // 36,864 B
    const int o0 = blockIdx.x * 32;
    const int n0 = blockIdx.y * 256;
    const int tid = threadIdx.x;
    const int n = n0 + tid;

    // chosen weight-row offsets (element units): ((o*8)+p)*1024
    unsigned wofs[32];
    #pragma unroll
    for (int oi = 0; oi < 32; ++oi) {
        const unsigned p = best[(size_t)(o0 + oi) * N_ + n];
        wofs[oi] = ((unsigned)(o0 + oi) * 8u + p) * 1024u;
    }

    float acc[32];
    #pragma unroll
    for (int oi = 0; oi < 32; ++oi) acc[oi] = 0.f;

    #pragma unroll 1
    for (int kc = 0; kc < I_; kc += 32) {
        __syncthreads();
        // cooperative X tile load: 256 rows x 8 float4
        #pragma unroll
        for (int it = 0; it < 8; ++it) {
            const int idx = it * 256 + tid;
            const int row = idx >> 3, c4 = idx & 7;
            const float4 v = *(const float4*)(X + (size_t)(n0 + row) * I_ + kc + c4 * 4);
            *(float4*)&x_lds[row * 36 + c4 * 4] = v;
        }
        __syncthreads();

        float4 xr[8];
        #pragma unroll
        for (int q = 0; q < 8; ++q) xr[q] = *(const float4*)&x_lds[tid * 36 + q * 4];

        #pragma unroll
        for (int oi = 0; oi < 32; ++oi) {
            const float* wp = W + wofs[oi] + kc;
            float a = acc[oi];
            #pragma unroll
            for (int q = 0; q < 8; ++q) {
                const float4 wv = *(const float4*)(wp + q * 4);
                a = fmaf(wv.x, xr[q].x, a);
                a = fmaf(wv.y, xr[q].y, a);
                a = fmaf(wv.z, xr[q].z, a);
                a = fmaf(wv.w, xr[q].w, a);
            }
            acc[oi] = a;
        }
    }

    // epilogue: bias + store (thread's 32 outputs are contiguous in out[n, :])
    float* op = out + (size_t)n * O_ + o0;
    #pragma unroll
    for (int oi4 = 0; oi4 < 8; ++oi4) {
        float4 v;
        v.x = acc[oi4 * 4 + 0] + bias[wofs[oi4 * 4 + 0] >> 10];
        v.y = acc[oi4 * 4 + 1] + bias[wofs[oi4 * 4 + 1] >> 10];
        v.z = acc[oi4 * 4 + 2] + bias[wofs[oi4 * 4 + 2] >> 10];
        v.w = acc[oi4 * 4 + 3] + bias[wofs[oi4 * 4 + 3] >> 10];
        *(float4*)(op + oi4 * 4) = v;
    }
}

// ---------------------------------------------------------------------------
extern "C" void kernel_launch(void* const* d_in, const int* in_sizes, int n_in,
                              void* d_out, int out_size, void* d_ws, size_t ws_size,
                              hipStream_t stream) {
    const float* X      = (const float*)d_in[0];
    const float* ctx    = (const float*)d_in[1];
    const float* W      = (const float*)d_in[2];
    const float* bias   = (const float*)d_in[3];
    const float* protos = (const float*)d_in[4];
    float* out = (float*)d_out;

    unsigned char* best = (unsigned char*)d_ws;                  // [O][N] = 8 MiB
    float* psq = (float*)((char*)d_ws + (size_t)O_ * N_);        // [O*P] = 32 KiB

    psq_kernel<<<dim3(32), dim3(256), 0, stream>>>(protos, psq);
    argmin_kernel<<<dim3(O_ / 8, N_ / 128), dim3(512), 0, stream>>>(ctx, protos, psq, best);
    gemm_sel_kernel<<<dim3(O_ / 32, N_ / 256), dim3(256), 0, stream>>>(X, W, bias, best, out);
}

// Round 2
// 778.054 us; speedup vs baseline: 4.9937x; 4.9937x over previous
//
#include <hip/hip_runtime.h>
#include <hip/hip_bf16.h>

#define N_ 8192
#define I_ 1024
#define O_ 1024
#define P_ 8
#define C_ 64
#define OP_ (O_ * P_)

typedef float f32x4 __attribute__((ext_vector_type(4)));
typedef __bf16 bf16x8 __attribute__((ext_vector_type(8)));
typedef unsigned short ushort8 __attribute__((ext_vector_type(8)));

#define GLOBAL_AS(p) ((const __attribute__((address_space(1))) unsigned int*)(p))
#define LDS_AS(p) ((__attribute__((address_space(3))) unsigned int*)(p))

// ---------------------------------------------------------------------------
// Kernel A0: proto_sq[o*8+p] = sum_c protos[o,p,c]^2
// ---------------------------------------------------------------------------
__global__ void psq_kernel(const float* __restrict__ protos, float* __restrict__ psq) {
    const int idx = blockIdx.x * 256 + threadIdx.x;  // 0..8191
    const float* pr = protos + (size_t)idx * C_;
    float s = 0.f;
    #pragma unroll
    for (int c = 0; c < C_; ++c) s = fmaf(pr[c], pr[c], s);
    psq[idx] = s;
}

// ---------------------------------------------------------------------------
// Kernel A: best[o][n] = argmin_p ( psq[o,p] - 2*<protos[o,p,:], ctx[n,:]> )
// fp32 pass; fp64 exact refine when margin < 4e-3. (verified correct, round 1)
// ---------------------------------------------------------------------------
__global__ __launch_bounds__(512, 4)
void argmin_kernel(const float* __restrict__ ctx, const float* __restrict__ protos,
                   const float* __restrict__ psq, unsigned char* __restrict__ best) {
    __shared__ float ctx_lds[128 * 68];
    const int o0 = blockIdx.x * 8;
    const int n0 = blockIdx.y * 128;
    const int tid = threadIdx.x;

    for (int it = tid; it < 128 * 16; it += 512) {
        const int row = it >> 4, c4 = it & 15;
        const float4 v = *(const float4*)(ctx + (size_t)(n0 + row) * C_ + c4 * 4);
        *(float4*)&ctx_lds[row * 68 + c4 * 4] = v;
    }
    __syncthreads();

    const int w = tid >> 6, l = tid & 63;
    const int o = o0 + w;
    const float* pr = protos + (size_t)o * (P_ * C_);

    float g[2][8];
    #pragma unroll
    for (int j = 0; j < 2; ++j)
        #pragma unroll
        for (int p = 0; p < 8; ++p) g[j][p] = 0.f;

    #pragma unroll 1
    for (int cc = 0; cc < C_; cc += 4) {
        float4 x[2];
        #pragma unroll
        for (int j = 0; j < 2; ++j)
            x[j] = *(const float4*)&ctx_lds[(l + 64 * j) * 68 + cc];
        #pragma unroll
        for (int p = 0; p < 8; ++p) {
            const float4 wv = *(const float4*)(pr + p * C_ + cc);
            #pragma unroll
            for (int j = 0; j < 2; ++j) {
                float a = g[j][p];
                a = fmaf(wv.x, x[j].x, a);
                a = fmaf(wv.y, x[j].y, a);
                a = fmaf(wv.z, x[j].z, a);
                a = fmaf(wv.w, x[j].w, a);
                g[j][p] = a;
            }
        }
    }

    float ps[8];
    #pragma unroll
    for (int p = 0; p < 8; ++p) ps[p] = psq[o * 8 + p];

    #pragma unroll
    for (int j = 0; j < 2; ++j) {
        float b1 = 3.4e38f, b2 = 3.4e38f;
        int bi = 0;
        #pragma unroll
        for (int p = 0; p < 8; ++p) {
            const float f = fmaf(-2.f, g[j][p], ps[p]);
            if (f < b1) { b2 = b1; b1 = f; bi = p; }
            else if (f < b2) { b2 = f; }
        }
        if (b2 - b1 < 4e-3f) {
            double d1 = 1e300;
            int bi2 = 0;
            for (int p = 0; p < 8; ++p) {
                double s = 0.0;
                const float* prow = pr + p * C_;
                const float* crow = &ctx_lds[(l + 64 * j) * 68];
                for (int c = 0; c < C_; ++c) {
                    const double pv = (double)prow[c];
                    const double cv = (double)crow[c];
                    s += pv * (pv - 2.0 * cv);
                }
                if (s < d1) { d1 = s; bi2 = p; }
            }
            bi = bi2;
        }
        best[(size_t)o * N_ + (n0 + l + 64 * j)] = (unsigned char)bi;
    }
}

// ---------------------------------------------------------------------------
// Kernel C: fp32 -> bf16 with pre-applied XOR chunk swizzle.
// dst[row][c] (8-bf16 chunks, c=0..127) = bf16(src[row][c ^ (row&7)])
// So a linear global_load_lds of dst rows yields an LDS tile whose
// ds_read at chunk (ct ^ (R&7)) returns the true chunk ct  (m173/m201).
// ---------------------------------------------------------------------------
__global__ __launch_bounds__(256)
void convert_swz_kernel(const float* __restrict__ src, unsigned short* __restrict__ dst) {
    const int idx = blockIdx.x * 256 + threadIdx.x;  // 8192*128 chunks
    const int row = idx >> 7;
    const int c = idx & 127;
    const int cs = c ^ (row & 7);
    const float* sp = src + (size_t)row * I_ + cs * 8;
    const float4 f0 = *(const float4*)(sp);
    const float4 f1 = *(const float4*)(sp + 4);
    ushort8 v;
    v[0] = __builtin_bit_cast(unsigned short, __float2bfloat16(f0.x));
    v[1] = __builtin_bit_cast(unsigned short, __float2bfloat16(f0.y));
    v[2] = __builtin_bit_cast(unsigned short, __float2bfloat16(f0.z));
    v[3] = __builtin_bit_cast(unsigned short, __float2bfloat16(f0.w));
    v[4] = __builtin_bit_cast(unsigned short, __float2bfloat16(f1.x));
    v[5] = __builtin_bit_cast(unsigned short, __float2bfloat16(f1.y));
    v[6] = __builtin_bit_cast(unsigned short, __float2bfloat16(f1.z));
    v[7] = __builtin_bit_cast(unsigned short, __float2bfloat16(f1.w));
    *(ushort8*)(dst + (size_t)row * I_ + c * 8) = v;
}

// ---------------------------------------------------------------------------
// Kernel B: bf16 MFMA GEMM C[n, op] = X[n,:] . W[op,:]  (both [rows][K=1024]),
// fused gather epilogue: out[n,o] = C[n, o*8+best[o][n]] + bias[o*8+best].
// m97 structure: 128x128 tile, BK=64, 4 waves (2x2), global_load_lds w=16,
// pre-swizzled sources + XOR on ds_read (bank-conflict-free).
// ---------------------------------------------------------------------------
__global__ __launch_bounds__(256, 3)
void gemm_gather_kernel(const unsigned short* __restrict__ Xb,
                        const unsigned short* __restrict__ Wb,
                        const float* __restrict__ bias,
                        const unsigned char* __restrict__ best,
                        float* __restrict__ out) {
    __shared__ unsigned short As[128 * 64];
    __shared__ unsigned short Bs[128 * 64];

    // XCD-aware swizzle (4096 blocks % 8 == 0 -> simple form is bijective)
    int wg = blockIdx.x;
    wg = (wg & 7) * 512 + (wg >> 3);
    const int bx = wg & 63;
    const int by = wg >> 6;
    const int n0 = by * 128;
    const int col0 = bx * 128;

    const int tid = threadIdx.x;
    const int w = tid >> 6, l = tid & 63;
    const int wr = w >> 1, wc = w & 1;
    const int lr = l & 15;  // fragment row selector
    const int lk = l >> 4;  // fragment k-chunk selector

    f32x4 acc[4][4];
    #pragma unroll
    for (int m = 0; m < 4; ++m)
        #pragma unroll
        for (int nf = 0; nf < 4; ++nf) acc[m][nf] = (f32x4)(0.f);

    #pragma unroll 1
    for (int kc = 0; kc < I_; kc += 64) {
        if (kc) __syncthreads();
        // stage A,B tiles: 16 x 1KB chunks each; wave w issues insts q=w*4+t
        #pragma unroll
        for (int t = 0; t < 4; ++t) {
            const int q = w * 4 + t;
            const int chunk = q * 64 + l;
            const int r = chunk >> 3, cq = chunk & 7;
            const unsigned short* ga = Xb + (size_t)(n0 + r) * I_ + kc + cq * 8;
            const unsigned short* gb = Wb + (size_t)(col0 + r) * I_ + kc + cq * 8;
            __builtin_amdgcn_global_load_lds(GLOBAL_AS(ga), LDS_AS(As + q * 512), 16, 0, 0);
            __builtin_amdgcn_global_load_lds(GLOBAL_AS(gb), LDS_AS(Bs + q * 512), 16, 0, 0);
        }
        __syncthreads();

        #pragma unroll
        for (int kk = 0; kk < 64; kk += 32) {
            bf16x8 af[4], bfr[4];
            const int ct = (kk >> 3) + lk;
            #pragma unroll
            for (int m = 0; m < 4; ++m) {
                const int R = wr * 64 + m * 16 + lr;
                af[m] = *(const bf16x8*)&As[R * 64 + ((ct ^ (R & 7)) << 3)];
            }
            #pragma unroll
            for (int nf = 0; nf < 4; ++nf) {
                const int R = wc * 64 + nf * 16 + lr;
                bfr[nf] = *(const bf16x8*)&Bs[R * 64 + ((ct ^ (R & 7)) << 3)];
            }
            #pragma unroll
            for (int m = 0; m < 4; ++m)
                #pragma unroll
                for (int nf = 0; nf < 4; ++nf)
                    acc[m][nf] = __builtin_amdgcn_mfma_f32_16x16x32_bf16(af[m], bfr[nf], acc[m][nf], 0, 0, 0);
        }
    }

    // epilogue: C row = n (from X), col = opcol (from W); col = lane&15,
    // row = (lane>>4)*4 + reg (verified m89/m91 layout)
    #pragma unroll
    for (int nf = 0; nf < 4; ++nf) {
        const int opcol = col0 + wc * 64 + nf * 16 + lr;
        const int o = opcol >> 3;
        const unsigned char p = (unsigned char)(opcol & 7);
        const float bv = bias[opcol];
        #pragma unroll
        for (int m = 0; m < 4; ++m) {
            #pragma unroll
            for (int j = 0; j < 4; ++j) {
                const int n = n0 + wr * 64 + m * 16 + lk * 4 + j;
                if (best[(size_t)o * N_ + n] == p)
                    out[(size_t)n * O_ + o] = acc[m][nf][j] + bv;
            }
        }
    }
}

// ---------------------------------------------------------------------------
extern "C" void kernel_launch(void* const* d_in, const int* in_sizes, int n_in,
                              void* d_out, int out_size, void* d_ws, size_t ws_size,
                              hipStream_t stream) {
    const float* X      = (const float*)d_in[0];
    const float* ctx    = (const float*)d_in[1];
    const float* W      = (const float*)d_in[2];
    const float* bias   = (const float*)d_in[3];
    const float* protos = (const float*)d_in[4];
    float* out = (float*)d_out;

    char* ws = (char*)d_ws;
    unsigned char* best = (unsigned char*)ws;                     // [O][N]  8 MiB
    float* psq = (float*)(ws + ((size_t)8 << 20));                // 32 KiB
    unsigned short* Xb = (unsigned short*)(ws + ((size_t)9 << 20));   // 16 MiB
    unsigned short* Wb = (unsigned short*)(ws + ((size_t)25 << 20));  // 16 MiB

    convert_swz_kernel<<<dim3(4096), dim3(256), 0, stream>>>(X, Xb);
    convert_swz_kernel<<<dim3(4096), dim3(256), 0, stream>>>(W, Wb);
    psq_kernel<<<dim3(32), dim3(256), 0, stream>>>(protos, psq);
    argmin_kernel<<<dim3(O_ / 8, N_ / 128), dim3(512), 0, stream>>>(ctx, protos, psq, best);
    gemm_gather_kernel<<<dim3(4096), dim3(256), 0, stream>>>(Xb, Wb, bias, best, out);
}

// Round 3
// 396.059 us; speedup vs baseline: 9.8101x; 1.9645x over previous
//
#include <hip/hip_runtime.h>
#include <hip/hip_bf16.h>

#define N_ 8192
#define I_ 1024
#define O_ 1024
#define P_ 8
#define C_ 64
#define OP_ (O_ * P_)
#define WL_CAP (1u << 20)

typedef float f32x4 __attribute__((ext_vector_type(4)));
typedef __bf16 bf16x8 __attribute__((ext_vector_type(8)));
typedef unsigned short ushort8 __attribute__((ext_vector_type(8)));

#define GLOBAL_AS(p) ((const __attribute__((address_space(1))) unsigned int*)(p))
#define LDS_AS(p) ((__attribute__((address_space(3))) unsigned int*)(p))

// ---------------------------------------------------------------------------
// Kernel A0: proto_sq[o*8+p] = sum_c protos[o,p,c]^2
// ---------------------------------------------------------------------------
__global__ void psq_kernel(const float* __restrict__ protos, float* __restrict__ psq) {
    const int idx = blockIdx.x * 256 + threadIdx.x;  // 0..8191
    const float* pr = protos + (size_t)idx * C_;
    float s = 0.f;
    #pragma unroll
    for (int c = 0; c < C_; ++c) s = fmaf(pr[c], pr[c], s);
    psq[idx] = s;
}

// ---------------------------------------------------------------------------
// Kernel A: argmin as register-tiled fp32 GEMM, M=N_ x N=OP_ x K=64.
// Block 256 thr, tile 128n x 128op; lane tile 8n x 8p (one o per lane).
// Near-ties (margin < 4e-3, same fp32 accum order as validated round-1)
// appended to worklist for exact fp64 refine in a separate kernel.
// ---------------------------------------------------------------------------
__global__ __launch_bounds__(256, 2)
void argmin_kernel(const float* __restrict__ ctx, const float* __restrict__ protos,
                   const float* __restrict__ psq, unsigned char* __restrict__ best,
                   unsigned* __restrict__ wl, unsigned* __restrict__ wl_cnt) {
    __shared__ float At[64][128];  // ctx transposed  [c][n_local]
    __shared__ float Bt[64][128];  // proto transposed [c][op_local]

    const int tid = threadIdx.x;
    const int op0 = blockIdx.x * 128;
    const int n0 = blockIdx.y * 128;

    // stage transposed: thread t -> row r = t>>1, half h = t&1 (32 c values)
    {
        const int r = tid >> 1, h = tid & 1;
        const float* gc = ctx + (size_t)(n0 + r) * C_ + h * 32;
        const float* gp = protos + (size_t)(op0 + r) * C_ + h * 32;
        #pragma unroll
        for (int j = 0; j < 8; ++j) {
            const float4 va = *(const float4*)(gc + j * 4);
            const float4 vb = *(const float4*)(gp + j * 4);
            const int c = h * 32 + j * 4;
            At[c + 0][r] = va.x; At[c + 1][r] = va.y; At[c + 2][r] = va.z; At[c + 3][r] = va.w;
            Bt[c + 0][r] = vb.x; Bt[c + 1][r] = vb.y; Bt[c + 2][r] = vb.z; Bt[c + 3][r] = vb.w;
        }
    }
    __syncthreads();

    const int w = tid >> 6, l = tid & 63;
    const int ln = l & 7, lp = l >> 3;
    const int na = (w >> 1) * 64 + ln * 8;  // n_local base
    const int ob = (w & 1) * 64 + lp * 8;   // op_local base (multiple of 8)

    float acc[8][8];
    #pragma unroll
    for (int i = 0; i < 8; ++i)
        #pragma unroll
        for (int j = 0; j < 8; ++j) acc[i][j] = 0.f;

    #pragma unroll 2
    for (int k = 0; k < 64; ++k) {
        const f32x4 a0 = *(const f32x4*)&At[k][na];
        const f32x4 a1 = *(const f32x4*)&At[k][na + 4];
        const f32x4 b0 = *(const f32x4*)&Bt[k][ob];
        const f32x4 b1 = *(const f32x4*)&Bt[k][ob + 4];
        float av[8] = {a0.x, a0.y, a0.z, a0.w, a1.x, a1.y, a1.z, a1.w};
        float bv[8] = {b0.x, b0.y, b0.z, b0.w, b1.x, b1.y, b1.z, b1.w};
        #pragma unroll
        for (int i = 0; i < 8; ++i)
            #pragma unroll
            for (int j = 0; j < 8; ++j)
                acc[i][j] = fmaf(av[i], bv[j], acc[i][j]);
    }

    const int o = (op0 + ob) >> 3;  // this lane's single o
    const f32x4 p0 = *(const f32x4*)(psq + o * 8);
    const f32x4 p1 = *(const f32x4*)(psq + o * 8 + 4);
    const float ps[8] = {p0.x, p0.y, p0.z, p0.w, p1.x, p1.y, p1.z, p1.w};

    unsigned long long bytes = 0;
    #pragma unroll
    for (int i = 0; i < 8; ++i) {
        float b1v = 3.4e38f, b2v = 3.4e38f;
        int bi = 0;
        #pragma unroll
        for (int p = 0; p < 8; ++p) {
            const float f = fmaf(-2.f, acc[i][p], ps[p]);
            if (f < b1v) { b2v = b1v; b1v = f; bi = p; }
            else if (f < b2v) { b2v = f; }
        }
        bytes |= (unsigned long long)bi << (i * 8);
        if (b2v - b1v < 4e-3f) {
            const unsigned idx = atomicAdd(wl_cnt, 1u);
            if (idx < WL_CAP) wl[idx] = (unsigned)(o * N_ + (n0 + na + i));
        }
    }
    *(unsigned long long*)&best[(size_t)o * N_ + (n0 + na)] = bytes;
}

// ---------------------------------------------------------------------------
// Kernel A2: exact fp64 refine of near-tie (n,o) pairs (rare, scattered).
// ---------------------------------------------------------------------------
__global__ __launch_bounds__(256)
void refine_kernel(const float* __restrict__ ctx, const float* __restrict__ protos,
                   const unsigned* __restrict__ wl, const unsigned* __restrict__ wl_cnt,
                   unsigned char* __restrict__ best) {
    const unsigned cnt = min(*wl_cnt, WL_CAP);
    for (unsigned i = blockIdx.x * 256 + threadIdx.x; i < cnt; i += gridDim.x * 256) {
        const unsigned e = wl[i];
        const int n = (int)(e & (N_ - 1));
        const int o = (int)(e >> 13);
        const float* cr = ctx + (size_t)n * C_;
        double d1 = 1e300;
        int bi = 0;
        for (int p = 0; p < 8; ++p) {
            const float* pr = protos + ((size_t)o * 8 + p) * C_;
            double s = 0.0;
            for (int c = 0; c < C_; ++c) {
                const double pv = (double)pr[c];
                const double cv = (double)cr[c];
                s += pv * (pv - 2.0 * cv);
            }
            if (s < d1) { d1 = s; bi = p; }
        }
        best[(size_t)o * N_ + n] = (unsigned char)bi;
    }
}

// ---------------------------------------------------------------------------
// Kernel C: fp32 -> bf16 with pre-applied XOR chunk swizzle (m173/m201).
// ---------------------------------------------------------------------------
__global__ __launch_bounds__(256)
void convert_swz_kernel(const float* __restrict__ src, unsigned short* __restrict__ dst) {
    const int idx = blockIdx.x * 256 + threadIdx.x;
    const int row = idx >> 7;
    const int c = idx & 127;
    const int cs = c ^ (row & 7);
    const float* sp = src + (size_t)row * I_ + cs * 8;
    const float4 f0 = *(const float4*)(sp);
    const float4 f1 = *(const float4*)(sp + 4);
    ushort8 v;
    v[0] = __builtin_bit_cast(unsigned short, __float2bfloat16(f0.x));
    v[1] = __builtin_bit_cast(unsigned short, __float2bfloat16(f0.y));
    v[2] = __builtin_bit_cast(unsigned short, __float2bfloat16(f0.z));
    v[3] = __builtin_bit_cast(unsigned short, __float2bfloat16(f0.w));
    v[4] = __builtin_bit_cast(unsigned short, __float2bfloat16(f1.x));
    v[5] = __builtin_bit_cast(unsigned short, __float2bfloat16(f1.y));
    v[6] = __builtin_bit_cast(unsigned short, __float2bfloat16(f1.z));
    v[7] = __builtin_bit_cast(unsigned short, __float2bfloat16(f1.w));
    *(ushort8*)(dst + (size_t)row * I_ + c * 8) = v;
}

// ---------------------------------------------------------------------------
// Kernel B: bf16 MFMA GEMM + fused gather epilogue (m97 structure, verified).
// ---------------------------------------------------------------------------
__global__ __launch_bounds__(256, 3)
void gemm_gather_kernel(const unsigned short* __restrict__ Xb,
                        const unsigned short* __restrict__ Wb,
                        const float* __restrict__ bias,
                        const unsigned char* __restrict__ best,
                        float* __restrict__ out) {
    __shared__ unsigned short As[128 * 64];
    __shared__ unsigned short Bs[128 * 64];

    int wg = blockIdx.x;
    wg = (wg & 7) * 512 + (wg >> 3);
    const int bx = wg & 63;
    const int by = wg >> 6;
    const int n0 = by * 128;
    const int col0 = bx * 128;

    const int tid = threadIdx.x;
    const int w = tid >> 6, l = tid & 63;
    const int wr = w >> 1, wc = w & 1;
    const int lr = l & 15;
    const int lk = l >> 4;

    f32x4 acc[4][4];
    #pragma unroll
    for (int m = 0; m < 4; ++m)
        #pragma unroll
        for (int nf = 0; nf < 4; ++nf) acc[m][nf] = (f32x4)(0.f);

    #pragma unroll 1
    for (int kc = 0; kc < I_; kc += 64) {
        if (kc) __syncthreads();
        #pragma unroll
        for (int t = 0; t < 4; ++t) {
            const int q = w * 4 + t;
            const int chunk = q * 64 + l;
            const int r = chunk >> 3, cq = chunk & 7;
            const unsigned short* ga = Xb + (size_t)(n0 + r) * I_ + kc + cq * 8;
            const unsigned short* gb = Wb + (size_t)(col0 + r) * I_ + kc + cq * 8;
            __builtin_amdgcn_global_load_lds(GLOBAL_AS(ga), LDS_AS(As + q * 512), 16, 0, 0);
            __builtin_amdgcn_global_load_lds(GLOBAL_AS(gb), LDS_AS(Bs + q * 512), 16, 0, 0);
        }
        __syncthreads();

        #pragma unroll
        for (int kk = 0; kk < 64; kk += 32) {
            bf16x8 af[4], bfr[4];
            const int ct = (kk >> 3) + lk;
            #pragma unroll
            for (int m = 0; m < 4; ++m) {
                const int R = wr * 64 + m * 16 + lr;
                af[m] = *(const bf16x8*)&As[R * 64 + ((ct ^ (R & 7)) << 3)];
            }
            #pragma unroll
            for (int nf = 0; nf < 4; ++nf) {
                const int R = wc * 64 + nf * 16 + lr;
                bfr[nf] = *(const bf16x8*)&Bs[R * 64 + ((ct ^ (R & 7)) << 3)];
            }
            #pragma unroll
            for (int m = 0; m < 4; ++m)
                #pragma unroll
                for (int nf = 0; nf < 4; ++nf)
                    acc[m][nf] = __builtin_amdgcn_mfma_f32_16x16x32_bf16(af[m], bfr[nf], acc[m][nf], 0, 0, 0);
        }
    }

    #pragma unroll
    for (int nf = 0; nf < 4; ++nf) {
        const int opcol = col0 + wc * 64 + nf * 16 + lr;
        const int o = opcol >> 3;
        const unsigned char p = (unsigned char)(opcol & 7);
        const float bv = bias[opcol];
        #pragma unroll
        for (int m = 0; m < 4; ++m) {
            #pragma unroll
            for (int j = 0; j < 4; ++j) {
                const int n = n0 + wr * 64 + m * 16 + lk * 4 + j;
                if (best[(size_t)o * N_ + n] == p)
                    out[(size_t)n * O_ + o] = acc[m][nf][j] + bv;
            }
        }
    }
}

// ---------------------------------------------------------------------------
extern "C" void kernel_launch(void* const* d_in, const int* in_sizes, int n_in,
                              void* d_out, int out_size, void* d_ws, size_t ws_size,
                              hipStream_t stream) {
    const float* X      = (const float*)d_in[0];
    const float* ctx    = (const float*)d_in[1];
    const float* W      = (const float*)d_in[2];
    const float* bias   = (const float*)d_in[3];
    const float* protos = (const float*)d_in[4];
    float* out = (float*)d_out;

    char* ws = (char*)d_ws;
    unsigned char* best = (unsigned char*)ws;                         // 8 MiB
    float* psq = (float*)(ws + ((size_t)8 << 20));                    // 32 KiB
    unsigned short* Xb = (unsigned short*)(ws + ((size_t)9 << 20));   // 16 MiB
    unsigned short* Wb = (unsigned short*)(ws + ((size_t)25 << 20));  // 16 MiB
    unsigned* wl_cnt = (unsigned*)(ws + ((size_t)41 << 20));          // 4 B
    unsigned* wl = (unsigned*)(ws + ((size_t)41 << 20) + 256);        // 4 MiB

    hipMemsetAsync(wl_cnt, 0, 4, stream);
    convert_swz_kernel<<<dim3(4096), dim3(256), 0, stream>>>(X, Xb);
    convert_swz_kernel<<<dim3(4096), dim3(256), 0, stream>>>(W, Wb);
    psq_kernel<<<dim3(32), dim3(256), 0, stream>>>(protos, psq);
    argmin_kernel<<<dim3(OP_ / 128, N_ / 128), dim3(256), 0, stream>>>(ctx, protos, psq, best, wl, wl_cnt);
    refine_kernel<<<dim3(64), dim3(256), 0, stream>>>(ctx, protos, wl, wl_cnt, best);
    gemm_gather_kernel<<<dim3(4096), dim3(256), 0, stream>>>(Xb, Wb, bias, best, out);
}

// Round 4
// 367.533 us; speedup vs baseline: 10.5715x; 1.0776x over previous
//
#include <hip/hip_runtime.h>
#include <hip/hip_bf16.h>

#define N_ 8192
#define I_ 1024
#define O_ 1024
#define P_ 8
#define C_ 64
#define OP_ (O_ * P_)
#define WL_CAP (1u << 20)

typedef float f32x4 __attribute__((ext_vector_type(4)));
typedef __bf16 bf16x8 __attribute__((ext_vector_type(8)));
typedef unsigned short ushort8 __attribute__((ext_vector_type(8)));

#define GLOBAL_AS(p) ((const __attribute__((address_space(1))) unsigned int*)(p))
#define LDS_AS(p) ((__attribute__((address_space(3))) unsigned int*)(p))

// ---------------------------------------------------------------------------
// Kernel A0: proto_sq[o*8+p] = sum_c protos[o,p,c]^2
// ---------------------------------------------------------------------------
__global__ void psq_kernel(const float* __restrict__ protos, float* __restrict__ psq) {
    const int idx = blockIdx.x * 256 + threadIdx.x;  // 0..8191
    const float* pr = protos + (size_t)idx * C_;
    float s = 0.f;
    #pragma unroll
    for (int c = 0; c < C_; ++c) s = fmaf(pr[c], pr[c], s);
    psq[idx] = s;
}

// ---------------------------------------------------------------------------
// Kernel A: argmin as register-tiled fp32 GEMM (validated round 3).
// ---------------------------------------------------------------------------
__global__ __launch_bounds__(256, 2)
void argmin_kernel(const float* __restrict__ ctx, const float* __restrict__ protos,
                   const float* __restrict__ psq, unsigned char* __restrict__ best,
                   unsigned* __restrict__ wl, unsigned* __restrict__ wl_cnt) {
    __shared__ float At[64][128];
    __shared__ float Bt[64][128];

    const int tid = threadIdx.x;
    const int op0 = blockIdx.x * 128;
    const int n0 = blockIdx.y * 128;

    {
        const int r = tid >> 1, h = tid & 1;
        const float* gc = ctx + (size_t)(n0 + r) * C_ + h * 32;
        const float* gp = protos + (size_t)(op0 + r) * C_ + h * 32;
        #pragma unroll
        for (int j = 0; j < 8; ++j) {
            const float4 va = *(const float4*)(gc + j * 4);
            const float4 vb = *(const float4*)(gp + j * 4);
            const int c = h * 32 + j * 4;
            At[c + 0][r] = va.x; At[c + 1][r] = va.y; At[c + 2][r] = va.z; At[c + 3][r] = va.w;
            Bt[c + 0][r] = vb.x; Bt[c + 1][r] = vb.y; Bt[c + 2][r] = vb.z; Bt[c + 3][r] = vb.w;
        }
    }
    __syncthreads();

    const int w = tid >> 6, l = tid & 63;
    const int ln = l & 7, lp = l >> 3;
    const int na = (w >> 1) * 64 + ln * 8;
    const int ob = (w & 1) * 64 + lp * 8;

    float acc[8][8];
    #pragma unroll
    for (int i = 0; i < 8; ++i)
        #pragma unroll
        for (int j = 0; j < 8; ++j) acc[i][j] = 0.f;

    #pragma unroll 2
    for (int k = 0; k < 64; ++k) {
        const f32x4 a0 = *(const f32x4*)&At[k][na];
        const f32x4 a1 = *(const f32x4*)&At[k][na + 4];
        const f32x4 b0 = *(const f32x4*)&Bt[k][ob];
        const f32x4 b1 = *(const f32x4*)&Bt[k][ob + 4];
        float av[8] = {a0.x, a0.y, a0.z, a0.w, a1.x, a1.y, a1.z, a1.w};
        float bv[8] = {b0.x, b0.y, b0.z, b0.w, b1.x, b1.y, b1.z, b1.w};
        #pragma unroll
        for (int i = 0; i < 8; ++i)
            #pragma unroll
            for (int j = 0; j < 8; ++j)
                acc[i][j] = fmaf(av[i], bv[j], acc[i][j]);
    }

    const int o = (op0 + ob) >> 3;
    const f32x4 p0 = *(const f32x4*)(psq + o * 8);
    const f32x4 p1 = *(const f32x4*)(psq + o * 8 + 4);
    const float ps[8] = {p0.x, p0.y, p0.z, p0.w, p1.x, p1.y, p1.z, p1.w};

    unsigned long long bytes = 0;
    #pragma unroll
    for (int i = 0; i < 8; ++i) {
        float b1v = 3.4e38f, b2v = 3.4e38f;
        int bi = 0;
        #pragma unroll
        for (int p = 0; p < 8; ++p) {
            const float f = fmaf(-2.f, acc[i][p], ps[p]);
            if (f < b1v) { b2v = b1v; b1v = f; bi = p; }
            else if (f < b2v) { b2v = f; }
        }
        bytes |= (unsigned long long)bi << (i * 8);
        if (b2v - b1v < 4e-3f) {
            const unsigned idx = atomicAdd(wl_cnt, 1u);
            if (idx < WL_CAP) wl[idx] = (unsigned)(o * N_ + (n0 + na + i));
        }
    }
    *(unsigned long long*)&best[(size_t)o * N_ + (n0 + na)] = bytes;
}

// ---------------------------------------------------------------------------
// Kernel A2: exact fp64 refine of near-tie (n,o) pairs.
// ---------------------------------------------------------------------------
__global__ __launch_bounds__(256)
void refine_kernel(const float* __restrict__ ctx, const float* __restrict__ protos,
                   const unsigned* __restrict__ wl, const unsigned* __restrict__ wl_cnt,
                   unsigned char* __restrict__ best) {
    const unsigned cnt = min(*wl_cnt, WL_CAP);
    for (unsigned i = blockIdx.x * 256 + threadIdx.x; i < cnt; i += gridDim.x * 256) {
        const unsigned e = wl[i];
        const int n = (int)(e & (N_ - 1));
        const int o = (int)(e >> 13);
        const float* cr = ctx + (size_t)n * C_;
        double d1 = 1e300;
        int bi = 0;
        for (int p = 0; p < 8; ++p) {
            const float* pr = protos + ((size_t)o * 8 + p) * C_;
            double s = 0.0;
            for (int c = 0; c < C_; ++c) {
                const double pv = (double)pr[c];
                const double cv = (double)cr[c];
                s += pv * (pv - 2.0 * cv);
            }
            if (s < d1) { d1 = s; bi = p; }
        }
        best[(size_t)o * N_ + n] = (unsigned char)bi;
    }
}

// ---------------------------------------------------------------------------
// Kernel C: fp32 -> bf16 with pre-applied XOR chunk swizzle (m173/m201).
// ---------------------------------------------------------------------------
__global__ __launch_bounds__(256)
void convert_swz_kernel(const float* __restrict__ src, unsigned short* __restrict__ dst) {
    const int idx = blockIdx.x * 256 + threadIdx.x;
    const int row = idx >> 7;
    const int c = idx & 127;
    const int cs = c ^ (row & 7);
    const float* sp = src + (size_t)row * I_ + cs * 8;
    const float4 f0 = *(const float4*)(sp);
    const float4 f1 = *(const float4*)(sp + 4);
    ushort8 v;
    v[0] = __builtin_bit_cast(unsigned short, __float2bfloat16(f0.x));
    v[1] = __builtin_bit_cast(unsigned short, __float2bfloat16(f0.y));
    v[2] = __builtin_bit_cast(unsigned short, __float2bfloat16(f0.z));
    v[3] = __builtin_bit_cast(unsigned short, __float2bfloat16(f0.w));
    v[4] = __builtin_bit_cast(unsigned short, __float2bfloat16(f1.x));
    v[5] = __builtin_bit_cast(unsigned short, __float2bfloat16(f1.y));
    v[6] = __builtin_bit_cast(unsigned short, __float2bfloat16(f1.z));
    v[7] = __builtin_bit_cast(unsigned short, __float2bfloat16(f1.w));
    *(ushort8*)(dst + (size_t)row * I_ + c * 8) = v;
}

// ---------------------------------------------------------------------------
// Kernel B: 256x256 8-phase bf16 MFMA GEMM (T2+T3+T4+T5) + fused gather.
// 512 thr = 8 waves (2M x 4N); per-wave 128x64 out; BK=64; LDS 128 KiB dbuf.
// Stagger per tile t: ds_read {A(m0-3)+B(n0-1) | B(n2-3) | A(m4-7) | -},
// stage {A1(t+1) | B1(t+1) | B0(t+2) | A0(t+2)}, vmcnt(4) once at P4.
// Every restage is barrier-separated from its region's last read; the P4
// vmcnt(4) (2 half-tiles in flight) drains all of tile t+1 before use.
// ---------------------------------------------------------------------------
__global__ __launch_bounds__(512, 2)
void gemm_gather_kernel(const unsigned short* __restrict__ Xb,
                        const unsigned short* __restrict__ Wb,
                        const float* __restrict__ bias,
                        const unsigned char* __restrict__ best,
                        float* __restrict__ out) {
    extern __shared__ unsigned short lds[];  // 2 x (A 256x64 + B 256x64) = 128 KiB

    int wg = blockIdx.x;                     // 1024 blocks, %8==0 -> bijective
    wg = (wg & 7) * 128 + (wg >> 3);
    const int bx = wg & 31;
    const int by = wg >> 5;
    const int n0 = by * 256;
    const int col0 = bx * 256;

    const int tid = threadIdx.x;
    const int w = tid >> 6, l = tid & 63;
    const int wr = w >> 2;       // 0..1  (M half)
    const int wc = w & 3;        // 0..3  (N quarter)
    const int lr = l & 15;
    const int lk = l >> 4;

    // LDS element offsets (ushort): per buffer bp: A at bp*32768, B at +16384
    #define A_R(bp) (lds + (bp) * 32768)
    #define B_R(bp) (lds + (bp) * 32768 + 16384)

    // stage one 128x64 half-tile: 2 x global_load_lds(16B) per thread
    #define STAGE(gbase, grow0, tt, lregion) do {                                   \
        const unsigned short* _g = (gbase) + (size_t)(grow0) * I_ + (tt) * 64;      \
        _Pragma("unroll")                                                           \
        for (int _ld = 0; _ld < 2; ++_ld) {                                         \
            const int _ch = _ld * 512 + tid;                                        \
            __builtin_amdgcn_global_load_lds(                                       \
                GLOBAL_AS(_g + (size_t)(_ch >> 3) * I_ + (_ch & 7) * 8),            \
                LDS_AS((lregion) + _ch * 8), 16, 0, 0);                             \
        }                                                                           \
    } while (0)

    f32x4 acc[8][4];
    #pragma unroll
    for (int m = 0; m < 8; ++m)
        #pragma unroll
        for (int n = 0; n < 4; ++n) acc[m][n] = (f32x4)(0.f);

    // ---- prologue: tile0 {A0,B0,B1,A1} + tile1 {B0,A0}; drain tile0 ----
    STAGE(Xb, n0,        0, A_R(0));            // A0(0)
    STAGE(Wb, col0,      0, B_R(0));            // B0(0)
    STAGE(Wb, col0 + 128, 0, B_R(0) + 8192);    // B1(0)
    STAGE(Xb, n0 + 128,  0, A_R(0) + 8192);     // A1(0)
    STAGE(Wb, col0,      1, B_R(1));            // B0(1)
    STAGE(Xb, n0,        1, A_R(1));            // A0(1)
    asm volatile("s_waitcnt vmcnt(4)" ::: "memory");
    __builtin_amdgcn_sched_barrier(0);
    __builtin_amdgcn_s_barrier();

    bf16x8 af[4][2], bf0[2][2], bf1[2][2];

    #define RD_A(mbase, bp) do {                                                     \
        _Pragma("unroll")                                                            \
        for (int _m = 0; _m < 4; ++_m)                                               \
            _Pragma("unroll")                                                        \
            for (int _k = 0; _k < 2; ++_k) {                                         \
                const int _R = wr * 128 + ((mbase) + _m) * 16 + lr;                  \
                af[_m][_k] = *(const bf16x8*)&A_R(bp)[_R * 64 +                      \
                                (((_k * 4 + lk) ^ (_R & 7)) << 3)];                  \
            }                                                                        \
    } while (0)

    #define RD_B(dst, nbase, bp) do {                                                \
        _Pragma("unroll")                                                            \
        for (int _n = 0; _n < 2; ++_n)                                               \
            _Pragma("unroll")                                                        \
            for (int _k = 0; _k < 2; ++_k) {                                         \
                const int _R = wc * 64 + ((nbase) + _n) * 16 + lr;                   \
                dst[_n][_k] = *(const bf16x8*)&B_R(bp)[_R * 64 +                     \
                                (((_k * 4 + lk) ^ (_R & 7)) << 3)];                  \
            }                                                                        \
    } while (0)

    #define WAIT_LGKM() do {                                                         \
        asm volatile("s_waitcnt lgkmcnt(0)" ::: "memory");                           \
        __builtin_amdgcn_sched_barrier(0);                                           \
    } while (0)

    #define MFMA16(mbase, bsrc, nbase) do {                                          \
        __builtin_amdgcn_s_setprio(1);                                               \
        _Pragma("unroll")                                                            \
        for (int _m = 0; _m < 4; ++_m)                                               \
            _Pragma("unroll")                                                        \
            for (int _n = 0; _n < 2; ++_n)                                           \
                _Pragma("unroll")                                                    \
                for (int _k = 0; _k < 2; ++_k)                                       \
                    acc[(mbase) + _m][(nbase) + _n] =                                \
                        __builtin_amdgcn_mfma_f32_16x16x32_bf16(                     \
                            af[_m][_k], bsrc[_n][_k], acc[(mbase) + _m][(nbase) + _n], 0, 0, 0); \
        __builtin_amdgcn_s_setprio(0);                                               \
    } while (0)

    #pragma unroll 2
    for (int t = 0; t < 16; ++t) {
        const int bp = t & 1;
        const int bq = bp ^ 1;

        // ---- P1: read A(m0-3)+B(n0-1); stage A1(t+1) ----
        RD_A(0, bp);
        RD_B(bf0, 0, bp);
        if (t + 1 < 16) STAGE(Xb, n0 + 128, t + 1, A_R(bq) + 8192);
        __builtin_amdgcn_s_barrier();
        WAIT_LGKM();
        MFMA16(0, bf0, 0);
        __builtin_amdgcn_s_barrier();

        // ---- P2: read B(n2-3); stage B1(t+1) ----
        RD_B(bf1, 2, bp);
        if (t + 1 < 16) STAGE(Wb, col0 + 128, t + 1, B_R(bq) + 8192);
        __builtin_amdgcn_s_barrier();
        WAIT_LGKM();
        MFMA16(0, bf1, 2);
        __builtin_amdgcn_s_barrier();

        // ---- P3: read A(m4-7); stage B0(t+2) ----
        RD_A(4, bp);
        if (t + 2 < 16) STAGE(Wb, col0, t + 2, B_R(bp));
        __builtin_amdgcn_s_barrier();
        WAIT_LGKM();
        MFMA16(4, bf0, 0);
        __builtin_amdgcn_s_barrier();

        // ---- P4: stage A0(t+2); vmcnt(4) drains tile t+1 ----
        if (t + 2 < 16) STAGE(Xb, n0, t + 2, A_R(bp));
        asm volatile("s_waitcnt vmcnt(4)" ::: "memory");
        __builtin_amdgcn_sched_barrier(0);
        __builtin_amdgcn_s_barrier();
        MFMA16(4, bf1, 2);
        __builtin_amdgcn_s_barrier();
    }

    // ---- epilogue: fused argmin-gather + bias ----
    #pragma unroll
    for (int nf = 0; nf < 4; ++nf) {
        const int opcol = col0 + wc * 64 + nf * 16 + lr;
        const int o = opcol >> 3;
        const unsigned char p = (unsigned char)(opcol & 7);
        const float bv = bias[opcol];
        #pragma unroll
        for (int m = 0; m < 8; ++m) {
            #pragma unroll
            for (int j = 0; j < 4; ++j) {
                const int n = n0 + wr * 128 + m * 16 + lk * 4 + j;
                if (best[(size_t)o * N_ + n] == p)
                    out[(size_t)n * O_ + o] = acc[m][nf][j] + bv;
            }
        }
    }
    #undef A_R
    #undef B_R
    #undef STAGE
    #undef RD_A
    #undef RD_B
    #undef WAIT_LGKM
    #undef MFMA16
}

// ---------------------------------------------------------------------------
extern "C" void kernel_launch(void* const* d_in, const int* in_sizes, int n_in,
                              void* d_out, int out_size, void* d_ws, size_t ws_size,
                              hipStream_t stream) {
    const float* X      = (const float*)d_in[0];
    const float* ctx    = (const float*)d_in[1];
    const float* W      = (const float*)d_in[2];
    const float* bias   = (const float*)d_in[3];
    const float* protos = (const float*)d_in[4];
    float* out = (float*)d_out;

    char* ws = (char*)d_ws;
    unsigned char* best = (unsigned char*)ws;                         // 8 MiB
    float* psq = (float*)(ws + ((size_t)8 << 20));                    // 32 KiB
    unsigned short* Xb = (unsigned short*)(ws + ((size_t)9 << 20));   // 16 MiB
    unsigned short* Wb = (unsigned short*)(ws + ((size_t)25 << 20));  // 16 MiB
    unsigned* wl_cnt = (unsigned*)(ws + ((size_t)41 << 20));          // 4 B
    unsigned* wl = (unsigned*)(ws + ((size_t)41 << 20) + 256);        // 4 MiB

    hipFuncSetAttribute((const void*)gemm_gather_kernel,
                        hipFuncAttributeMaxDynamicSharedMemorySize, 131072);

    hipMemsetAsync(wl_cnt, 0, 4, stream);
    convert_swz_kernel<<<dim3(4096), dim3(256), 0, stream>>>(X, Xb);
    convert_swz_kernel<<<dim3(4096), dim3(256), 0, stream>>>(W, Wb);
    psq_kernel<<<dim3(32), dim3(256), 0, stream>>>(protos, psq);
    argmin_kernel<<<dim3(OP_ / 128, N_ / 128), dim3(256), 0, stream>>>(ctx, protos, psq, best, wl, wl_cnt);
    refine_kernel<<<dim3(64), dim3(256), 0, stream>>>(ctx, protos, wl, wl_cnt, best);
    gemm_gather_kernel<<<dim3(1024), dim3(512), 131072, stream>>>(Xb, Wb, bias, best, out);
}

// Round 5
// 347.213 us; speedup vs baseline: 11.1901x; 1.0585x over previous
//
#include <hip/hip_runtime.h>
#include <hip/hip_bf16.h>

#define N_ 8192
#define I_ 1024
#define O_ 1024
#define P_ 8
#define C_ 64
#define OP_ (O_ * P_)
#define WL_CAP (1u << 20)

typedef float f32x4 __attribute__((ext_vector_type(4)));
typedef __bf16 bf16x8 __attribute__((ext_vector_type(8)));
typedef unsigned short ushort8 __attribute__((ext_vector_type(8)));

#define GLOBAL_AS(p) ((const __attribute__((address_space(1))) unsigned int*)(p))
#define LDS_AS(p) ((__attribute__((address_space(3))) unsigned int*)(p))

// ---------------------------------------------------------------------------
// Kernel A0: proto_sq[o*8+p] = sum_c protos[o,p,c]^2
// ---------------------------------------------------------------------------
__global__ void psq_kernel(const float* __restrict__ protos, float* __restrict__ psq) {
    const int idx = blockIdx.x * 256 + threadIdx.x;  // 0..8191
    const float* pr = protos + (size_t)idx * C_;
    float s = 0.f;
    #pragma unroll
    for (int c = 0; c < C_; ++c) s = fmaf(pr[c], pr[c], s);
    psq[idx] = s;
}

// ---------------------------------------------------------------------------
// Kernel A: argmin as register-tiled fp32 GEMM (validated rounds 3-4).
// ---------------------------------------------------------------------------
__global__ __launch_bounds__(256, 2)
void argmin_kernel(const float* __restrict__ ctx, const float* __restrict__ protos,
                   const float* __restrict__ psq, unsigned char* __restrict__ best,
                   unsigned* __restrict__ wl, unsigned* __restrict__ wl_cnt) {
    __shared__ float At[64][128];
    __shared__ float Bt[64][128];

    const int tid = threadIdx.x;
    const int op0 = blockIdx.x * 128;
    const int n0 = blockIdx.y * 128;

    {
        const int r = tid >> 1, h = tid & 1;
        const float* gc = ctx + (size_t)(n0 + r) * C_ + h * 32;
        const float* gp = protos + (size_t)(op0 + r) * C_ + h * 32;
        #pragma unroll
        for (int j = 0; j < 8; ++j) {
            const float4 va = *(const float4*)(gc + j * 4);
            const float4 vb = *(const float4*)(gp + j * 4);
            const int c = h * 32 + j * 4;
            At[c + 0][r] = va.x; At[c + 1][r] = va.y; At[c + 2][r] = va.z; At[c + 3][r] = va.w;
            Bt[c + 0][r] = vb.x; Bt[c + 1][r] = vb.y; Bt[c + 2][r] = vb.z; Bt[c + 3][r] = vb.w;
        }
    }
    __syncthreads();

    const int w = tid >> 6, l = tid & 63;
    const int ln = l & 7, lp = l >> 3;
    const int na = (w >> 1) * 64 + ln * 8;
    const int ob = (w & 1) * 64 + lp * 8;

    float acc[8][8];
    #pragma unroll
    for (int i = 0; i < 8; ++i)
        #pragma unroll
        for (int j = 0; j < 8; ++j) acc[i][j] = 0.f;

    #pragma unroll 2
    for (int k = 0; k < 64; ++k) {
        const f32x4 a0 = *(const f32x4*)&At[k][na];
        const f32x4 a1 = *(const f32x4*)&At[k][na + 4];
        const f32x4 b0 = *(const f32x4*)&Bt[k][ob];
        const f32x4 b1 = *(const f32x4*)&Bt[k][ob + 4];
        float av[8] = {a0.x, a0.y, a0.z, a0.w, a1.x, a1.y, a1.z, a1.w};
        float bv[8] = {b0.x, b0.y, b0.z, b0.w, b1.x, b1.y, b1.z, b1.w};
        #pragma unroll
        for (int i = 0; i < 8; ++i)
            #pragma unroll
            for (int j = 0; j < 8; ++j)
                acc[i][j] = fmaf(av[i], bv[j], acc[i][j]);
    }

    const int o = (op0 + ob) >> 3;
    const f32x4 p0 = *(const f32x4*)(psq + o * 8);
    const f32x4 p1 = *(const f32x4*)(psq + o * 8 + 4);
    const float ps[8] = {p0.x, p0.y, p0.z, p0.w, p1.x, p1.y, p1.z, p1.w};

    unsigned long long bytes = 0;
    #pragma unroll
    for (int i = 0; i < 8; ++i) {
        float b1v = 3.4e38f, b2v = 3.4e38f;
        int bi = 0;
        #pragma unroll
        for (int p = 0; p < 8; ++p) {
            const float f = fmaf(-2.f, acc[i][p], ps[p]);
            if (f < b1v) { b2v = b1v; b1v = f; bi = p; }
            else if (f < b2v) { b2v = f; }
        }
        bytes |= (unsigned long long)bi << (i * 8);
        if (b2v - b1v < 4e-3f) {
            const unsigned idx = atomicAdd(wl_cnt, 1u);
            if (idx < WL_CAP) wl[idx] = (unsigned)(o * N_ + (n0 + na + i));
        }
    }
    *(unsigned long long*)&best[(size_t)o * N_ + (n0 + na)] = bytes;
}

// ---------------------------------------------------------------------------
// Kernel A2: exact fp64 refine of near-tie (n,o) pairs.
// ---------------------------------------------------------------------------
__global__ __launch_bounds__(256)
void refine_kernel(const float* __restrict__ ctx, const float* __restrict__ protos,
                   const unsigned* __restrict__ wl, const unsigned* __restrict__ wl_cnt,
                   unsigned char* __restrict__ best) {
    const unsigned cnt = min(*wl_cnt, WL_CAP);
    for (unsigned i = blockIdx.x * 256 + threadIdx.x; i < cnt; i += gridDim.x * 256) {
        const unsigned e = wl[i];
        const int n = (int)(e & (N_ - 1));
        const int o = (int)(e >> 13);
        const float* cr = ctx + (size_t)n * C_;
        double d1 = 1e300;
        int bi = 0;
        for (int p = 0; p < 8; ++p) {
            const float* pr = protos + ((size_t)o * 8 + p) * C_;
            double s = 0.0;
            for (int c = 0; c < C_; ++c) {
                const double pv = (double)pr[c];
                const double cv = (double)cr[c];
                s += pv * (pv - 2.0 * cv);
            }
            if (s < d1) { d1 = s; bi = p; }
        }
        best[(size_t)o * N_ + n] = (unsigned char)bi;
    }
}

// ---------------------------------------------------------------------------
// Kernel C: fp32 -> bf16 into the tiled-swizzled layout.
// 16B-chunk index idx = rp*256 + t*8 + j  (rp = row>>1, t = K-tile of 32, j=0..7)
// holds logical octet c = j ^ (rp&7):  row = 2rp + (c>>2), k0 = t*32 + (c&3)*8.
// A linear global_load_lds fill of (rp,t,*) then yields the XOR-swizzled
// 128B-rowpair LDS image (rule 21: linear dest + inverse-swz source).
// ---------------------------------------------------------------------------
__global__ __launch_bounds__(256)
void convert_swz_kernel(const float* __restrict__ src, unsigned short* __restrict__ dst) {
    const int idx = blockIdx.x * 256 + threadIdx.x;  // 1,048,576 chunks
    const int rp = idx >> 8;
    const int t = (idx >> 3) & 31;
    const int j = idx & 7;
    const int c = j ^ (rp & 7);
    const int row = rp * 2 + (c >> 2);
    const int k0 = t * 32 + (c & 3) * 8;
    const float* sp = src + (size_t)row * I_ + k0;
    const float4 f0 = *(const float4*)(sp);
    const float4 f1 = *(const float4*)(sp + 4);
    ushort8 v;
    v[0] = __builtin_bit_cast(unsigned short, __float2bfloat16(f0.x));
    v[1] = __builtin_bit_cast(unsigned short, __float2bfloat16(f0.y));
    v[2] = __builtin_bit_cast(unsigned short, __float2bfloat16(f0.z));
    v[3] = __builtin_bit_cast(unsigned short, __float2bfloat16(f0.w));
    v[4] = __builtin_bit_cast(unsigned short, __float2bfloat16(f1.x));
    v[5] = __builtin_bit_cast(unsigned short, __float2bfloat16(f1.y));
    v[6] = __builtin_bit_cast(unsigned short, __float2bfloat16(f1.z));
    v[7] = __builtin_bit_cast(unsigned short, __float2bfloat16(f1.w));
    *(ushort8*)(dst + (size_t)idx * 8) = v;
}

// ---------------------------------------------------------------------------
// Kernel B: ring-3 bf16 MFMA GEMM. 256x256 tile, BK=32, 32 K-tiles,
// 3 LDS buffers (96 KiB), 1 barrier/tile, counted lgkmcnt/vmcnt, setprio.
// Staging for tile t+2 issues during tile t, drains end of t+1 (~2 tiles of
// latency cover). Fused argmin-gather epilogue with u32 best loads.
// ---------------------------------------------------------------------------
__global__ __launch_bounds__(512, 1)
void gemm_gather_kernel(const unsigned short* __restrict__ Xb,
                        const unsigned short* __restrict__ Wb,
                        const float* __restrict__ bias,
                        const unsigned char* __restrict__ best,
                        float* __restrict__ out) {
    extern __shared__ unsigned short lds[];  // 3 x (A 16KB + B 16KB) = 96 KiB

    int wg = blockIdx.x;                     // 1024 blocks, %8==0 -> bijective
    wg = (wg & 7) * 128 + (wg >> 3);
    const int bx = wg & 31;
    const int by = wg >> 5;
    const int n0 = by * 256;
    const int col0 = bx * 256;

    const int tid = threadIdx.x;
    const int w = tid >> 6, l = tid & 63;
    const int wr = w >> 2;       // 0..1  (M half)
    const int wc = w & 3;        // 0..3  (N quarter)
    const int lr = l & 15;
    const int lk = l >> 4;

    // buffer bb: A chunks at bb*16384, B at bb*16384 + 8192 (ushort units)
    // stage one operand tile (256 rows x 32 k = 1024 chunks): 2 loads/thread
    #define STAGE(gsrc, rpg0, tt, ldsbase) do {                                     \
        _Pragma("unroll")                                                           \
        for (int _ld = 0; _ld < 2; ++_ld) {                                         \
            const int _L = _ld * 512 + tid;                                         \
            __builtin_amdgcn_global_load_lds(                                       \
                GLOBAL_AS((gsrc) + (((size_t)((rpg0) + (_L >> 3)) * 256 +           \
                                     (size_t)(tt) * 8 + (_L & 7)) * 8)),            \
                LDS_AS((ldsbase) + _L * 8), 16, 0, 0);                              \
        }                                                                           \
    } while (0)

    f32x4 acc[8][4];
    #pragma unroll
    for (int m = 0; m < 8; ++m)
        #pragma unroll
        for (int n = 0; n < 4; ++n) acc[m][n] = (f32x4)(0.f);

    const int rpgA = n0 >> 1;
    const int rpgB = col0 >> 1;

    // ---- prologue: stage tiles 0,1; drain tile 0 ----
    STAGE(Xb, rpgA, 0, lds);
    STAGE(Wb, rpgB, 0, lds + 8192);
    STAGE(Xb, rpgA, 1, lds + 16384);
    STAGE(Wb, rpgB, 1, lds + 16384 + 8192);
    asm volatile("s_waitcnt vmcnt(4)" ::: "memory");
    __builtin_amdgcn_sched_barrier(0);
    __builtin_amdgcn_s_barrier();

    bf16x8 af0[4], af1[4], bf[4];

    #define RD_A(dst, mbase, bb) do {                                                \
        _Pragma("unroll")                                                            \
        for (int _m = 0; _m < 4; ++_m) {                                             \
            const int _R = wr * 128 + ((mbase) + _m) * 16 + lr;                      \
            const int _rp = _R >> 1;                                                 \
            const int _j = (((_R & 1) << 2) + lk) ^ (_rp & 7);                       \
            dst[_m] = *(const bf16x8*)&lds[(bb) * 16384 + _rp * 64 + _j * 8];        \
        }                                                                            \
    } while (0)

    #define RD_B(bb) do {                                                            \
        _Pragma("unroll")                                                            \
        for (int _n = 0; _n < 4; ++_n) {                                             \
            const int _R = wc * 64 + _n * 16 + lr;                                   \
            const int _rp = _R >> 1;                                                 \
            const int _j = (((_R & 1) << 2) + lk) ^ (_rp & 7);                       \
            bf[_n] = *(const bf16x8*)&lds[(bb) * 16384 + 8192 + _rp * 64 + _j * 8];  \
        }                                                                            \
    } while (0)

    #define MFMA16(src, mbase) do {                                                  \
        __builtin_amdgcn_s_setprio(1);                                               \
        _Pragma("unroll")                                                            \
        for (int _m = 0; _m < 4; ++_m)                                               \
            _Pragma("unroll")                                                        \
            for (int _n = 0; _n < 4; ++_n)                                           \
                acc[(mbase) + _m][_n] =                                              \
                    __builtin_amdgcn_mfma_f32_16x16x32_bf16(                         \
                        src[_m], bf[_n], acc[(mbase) + _m][_n], 0, 0, 0);            \
        __builtin_amdgcn_s_setprio(0);                                               \
    } while (0)

    // ---- main loop: tiles 0..29 stage t+2; ring buffer b = t%3 ----
    #pragma unroll 3
    for (int t = 0; t < 30; ++t) {
        const int b = t % 3;
        const int s = (t + 2) % 3;
        RD_A(af0, 0, b);
        RD_B(b);
        RD_A(af1, 4, b);
        STAGE(Xb, rpgA, t + 2, lds + s * 16384);
        STAGE(Wb, rpgB, t + 2, lds + s * 16384 + 8192);
        asm volatile("s_waitcnt lgkmcnt(4)" ::: "memory");
        __builtin_amdgcn_sched_barrier(0);
        MFMA16(af0, 0);
        asm volatile("s_waitcnt lgkmcnt(0)" ::: "memory");
        __builtin_amdgcn_sched_barrier(0);
        MFMA16(af1, 4);
        asm volatile("s_waitcnt vmcnt(4)" ::: "memory");
        __builtin_amdgcn_sched_barrier(0);
        __builtin_amdgcn_s_barrier();
    }
    // ---- tile 30 (no stage; drain tile 31) ----
    {
        RD_A(af0, 0, 0);
        RD_B(0);
        RD_A(af1, 4, 0);
        asm volatile("s_waitcnt lgkmcnt(4)" ::: "memory");
        __builtin_amdgcn_sched_barrier(0);
        MFMA16(af0, 0);
        asm volatile("s_waitcnt lgkmcnt(0)" ::: "memory");
        __builtin_amdgcn_sched_barrier(0);
        MFMA16(af1, 4);
        asm volatile("s_waitcnt vmcnt(0)" ::: "memory");
        __builtin_amdgcn_sched_barrier(0);
        __builtin_amdgcn_s_barrier();
    }
    // ---- tile 31 ----
    {
        RD_A(af0, 0, 1);
        RD_B(1);
        RD_A(af1, 4, 1);
        asm volatile("s_waitcnt lgkmcnt(4)" ::: "memory");
        __builtin_amdgcn_sched_barrier(0);
        MFMA16(af0, 0);
        asm volatile("s_waitcnt lgkmcnt(0)" ::: "memory");
        __builtin_amdgcn_sched_barrier(0);
        MFMA16(af1, 4);
    }

    // ---- epilogue: fused argmin-gather + bias; u32 best loads ----
    const int nbase = n0 + wr * 128 + lk * 4;
    #pragma unroll
    for (int nf = 0; nf < 4; ++nf) {
        const int opcol = col0 + wc * 64 + nf * 16 + lr;
        const int o = opcol >> 3;
        const unsigned p = (unsigned)(opcol & 7);
        const float bv = bias[opcol];
        const unsigned char* brow = best + (size_t)o * N_ + nbase;
        #pragma unroll
        for (int m = 0; m < 8; ++m) {
            const unsigned b4 = *(const unsigned*)(brow + m * 16);
            #pragma unroll
            for (int j = 0; j < 4; ++j) {
                if (((b4 >> (j * 8)) & 255u) == p) {
                    const int n = nbase + m * 16 + j;
                    out[(size_t)n * O_ + o] = acc[m][nf][j] + bv;
                }
            }
        }
    }
    #undef STAGE
    #undef RD_A
    #undef RD_B
    #undef MFMA16
}

// ---------------------------------------------------------------------------
extern "C" void kernel_launch(void* const* d_in, const int* in_sizes, int n_in,
                              void* d_out, int out_size, void* d_ws, size_t ws_size,
                              hipStream_t stream) {
    const float* X      = (const float*)d_in[0];
    const float* ctx    = (const float*)d_in[1];
    const float* W      = (const float*)d_in[2];
    const float* bias   = (const float*)d_in[3];
    const float* protos = (const float*)d_in[4];
    float* out = (float*)d_out;

    char* ws = (char*)d_ws;
    unsigned char* best = (unsigned char*)ws;                         // 8 MiB
    float* psq = (float*)(ws + ((size_t)8 << 20));                    // 32 KiB
    unsigned short* Xb = (unsigned short*)(ws + ((size_t)9 << 20));   // 16 MiB
    unsigned short* Wb = (unsigned short*)(ws + ((size_t)25 << 20));  // 16 MiB
    unsigned* wl_cnt = (unsigned*)(ws + ((size_t)41 << 20));          // 4 B
    unsigned* wl = (unsigned*)(ws + ((size_t)41 << 20) + 256);        // 4 MiB

    hipFuncSetAttribute((const void*)gemm_gather_kernel,
                        hipFuncAttributeMaxDynamicSharedMemorySize, 98304);

    hipMemsetAsync(wl_cnt, 0, 4, stream);
    convert_swz_kernel<<<dim3(4096), dim3(256), 0, stream>>>(X, Xb);
    convert_swz_kernel<<<dim3(4096), dim3(256), 0, stream>>>(W, Wb);
    psq_kernel<<<dim3(32), dim3(256), 0, stream>>>(protos, psq);
    argmin_kernel<<<dim3(OP_ / 128, N_ / 128), dim3(256), 0, stream>>>(ctx, protos, psq, best, wl, wl_cnt);
    refine_kernel<<<dim3(64), dim3(256), 0, stream>>>(ctx, protos, wl, wl_cnt, best);
    gemm_gather_kernel<<<dim3(1024), dim3(512), 98304, stream>>>(Xb, Wb, bias, best, out);
}